// Round 1
// baseline (2295.478 us; speedup 1.0000x reference)
//
#include <hip/hip_runtime.h>
#include <stdint.h>

#define DEV __device__ __forceinline__

// ---------- helpers ----------
DEV unsigned short f2bf(float f) {
    union { float f; uint32_t u; } v; v.f = f;
    uint32_t u = v.u;
    return (unsigned short)((u + 0x7fffu + ((u >> 16) & 1u)) >> 16);  // RNE
}
DEV float silu_f(float x) { return x / (1.0f + __expf(-x)); }

// degree-3 B-spline bases on uniform grid g[j] = 0.4*(j-3) - 1, j=0..11 -> 8 bases
DEV void bspline8(float x, float* bo) {
    float b[11];
#pragma unroll
    for (int j = 0; j < 11; ++j) {
        float gj  = 0.4f * (float)(j - 3) - 1.0f;
        float gj1 = 0.4f * (float)(j - 2) - 1.0f;
        b[j] = (x >= gj && x < gj1) ? 1.0f : 0.0f;
    }
#pragma unroll
    for (int k = 1; k <= 3; ++k) {
        float inv = 1.0f / (0.4f * (float)k);
#pragma unroll
        for (int j = 0; j + k < 11; ++j) {
            float gj  = 0.4f * (float)(j - 3) - 1.0f;      // g[j]
            float gk1 = 0.4f * (float)(j + k - 2) - 1.0f;  // g[j+k+1]
            b[j] = ((x - gj) * b[j] + (gk1 - x) * b[j + 1]) * inv;
        }
    }
#pragma unroll
    for (int j = 0; j < 8; ++j) bo[j] = b[j];
}

// ---------- weight fold: Wc[o, i*9+0]=bw, [i*9+1+j]=sw*sc (bf16) ----------
__global__ __launch_bounds__(256) void wc_kernel(const float* __restrict__ bw,
        const float* __restrict__ sw, const float* __restrict__ sc,
        unsigned short* __restrict__ Wc, int total) {
    int idx = blockIdx.x * 256 + threadIdx.x;       // idx = o*IN + i
    if (idx >= total) return;
    float scale = sc[idx];
    unsigned short* o = Wc + (size_t)idx * 9;
    o[0] = f2bf(bw[idx]);
    const float* s = sw + (size_t)idx * 8;
#pragma unroll
    for (int j = 0; j < 8; ++j) o[1 + j] = f2bf(s[j] * scale);
}

// ---------- feature expansion: F[t, i*9+j] (bf16), X contiguous (t,i) ----------
__global__ __launch_bounds__(256) void feat_kernel(const float* __restrict__ X,
        unsigned short* __restrict__ F, int total) {
    int idx = blockIdx.x * 256 + threadIdx.x;
    if (idx >= total) return;
    float x = X[idx];
    unsigned short* o = F + (size_t)idx * 9;
    o[0] = f2bf(silu_f(x));
    float bo[8];
    bspline8(x, bo);
#pragma unroll
    for (int j = 0; j < 8; ++j) o[1 + j] = f2bf(bo[j]);
}

// ---------- GEMM: C[M,N] = A[M,K](bf16) * B[N,K](bf16)^T, f32 acc ----------
// M%64==0, N%64==0, K%32==0
__global__ __launch_bounds__(256) void gemm64(const unsigned short* __restrict__ A,
        const unsigned short* __restrict__ B, float* __restrict__ C,
        int M, int N, int K) {
    constexpr int PADW = 17;                 // dwords per row (16 data + 1 pad)
    __shared__ uint32_t As32[64 * PADW];
    __shared__ uint32_t Bs32[64 * PADW];
    int tid = threadIdx.x;
    int tx = tid & 15, ty = tid >> 4;
    int bm = blockIdx.x * 64, bn = blockIdx.y * 64;
    int lr = tid >> 2;                       // staging row 0..63
    int lc = (tid & 3) * 8;                  // staging col (elements)
    const unsigned short* pa = A + (size_t)(bm + lr) * K + lc;
    const unsigned short* pb = B + (size_t)(bn + lr) * K + lc;
    uint32_t* wa = &As32[lr * PADW + (lc >> 1)];
    uint32_t* wb = &Bs32[lr * PADW + (lc >> 1)];
    float acc[4][4] = {};
    for (int k0 = 0; k0 < K; k0 += 32) {
        uint4 va = *(const uint4*)pa;
        uint4 vb = *(const uint4*)pb;
        pa += 32; pb += 32;
        wa[0] = va.x; wa[1] = va.y; wa[2] = va.z; wa[3] = va.w;
        wb[0] = vb.x; wb[1] = vb.y; wb[2] = vb.z; wb[3] = vb.w;
        __syncthreads();
#pragma unroll
        for (int kk = 0; kk < 16; ++kk) {    // 2 K-steps per iter
            float a0[4], a1[4], b0[4], b1[4];
#pragma unroll
            for (int i = 0; i < 4; ++i) {
                uint32_t u = As32[(ty * 4 + i) * PADW + kk];
                union { uint32_t u; float f; } lo, hi;
                lo.u = u << 16; hi.u = u & 0xffff0000u;
                a0[i] = lo.f; a1[i] = hi.f;
            }
#pragma unroll
            for (int j = 0; j < 4; ++j) {
                uint32_t u = Bs32[(tx * 4 + j) * PADW + kk];
                union { uint32_t u; float f; } lo, hi;
                lo.u = u << 16; hi.u = u & 0xffff0000u;
                b0[j] = lo.f; b1[j] = hi.f;
            }
#pragma unroll
            for (int i = 0; i < 4; ++i)
#pragma unroll
                for (int j = 0; j < 4; ++j)
                    acc[i][j] = fmaf(a0[i], b0[j], fmaf(a1[i], b1[j], acc[i][j]));
        }
        __syncthreads();
    }
#pragma unroll
    for (int i = 0; i < 4; ++i) {
        float4 v; v.x = acc[i][0]; v.y = acc[i][1]; v.z = acc[i][2]; v.w = acc[i][3];
        *(float4*)&C[(size_t)(bm + ty * 4 + i) * N + bn + tx * 4] = v;
    }
}

// ---------- causal depthwise conv1d + SiLU + build xs (fwd & L-reversed) ----------
__global__ __launch_bounds__(256) void conv_xs_kernel(const float* __restrict__ xz,
        const float* __restrict__ cw, const float* __restrict__ cb,
        float* __restrict__ xs) {
    int idx = blockIdx.x * 256 + threadIdx.x;     // (bn, l, d)
    int d = idx & 511;
    int l = (idx >> 9) & 1023;
    int bn = idx >> 19;                           // 0..3
    const float* xcol = xz + (size_t)(bn * 1024) * 1024 + d;  // x = first half of xz row
    float acc = cb[d];
#pragma unroll
    for (int h = 0; h < 4; ++h) {
        int ls = l - 3 + h;
        float xv = (ls >= 0) ? xcol[(size_t)ls * 1024] : 0.0f;
        acc = fmaf(cw[d * 4 + h], xv, acc);
    }
    float v = silu_f(acc);
    int b = bn >> 1, nn = bn & 1;
    xs[((size_t)(b * 4 + nn) * 1024 + l) * 512 + d] = v;
    xs[((size_t)(b * 4 + nn + 2) * 1024 + (1023 - l)) * 512 + d] = v;
}

// ---------- delta = softplus(dt @ dt_w^T + dt_bias[k]) ----------
__global__ __launch_bounds__(256) void delta_kernel(const float* __restrict__ xdbl,
        const float* __restrict__ dtw, const float* __restrict__ dtb,
        float* __restrict__ delta) {
    int t = blockIdx.x >> 1;                 // token 0..8191
    int half = blockIdx.x & 1;
    int d = half * 256 + threadIdx.x;
    __shared__ float dtv[32];
    if (threadIdx.x < 32) dtv[threadIdx.x] = xdbl[(size_t)t * 64 + threadIdx.x];
    __syncthreads();
    const float* w = dtw + (size_t)d * 32;
    float acc = 0.0f;
#pragma unroll
    for (int r = 0; r < 32; r += 4) {
        float4 wv = *(const float4*)(w + r);
        acc = fmaf(dtv[r], wv.x, acc);
        acc = fmaf(dtv[r + 1], wv.y, acc);
        acc = fmaf(dtv[r + 2], wv.z, acc);
        acc = fmaf(dtv[r + 3], wv.w, acc);
    }
    int k = (t >> 10) & 3;
    float x = acc + dtb[k * 512 + d];
    float sp = (x > 20.0f) ? x : log1pf(__expf(x));
    delta[(size_t)t * 512 + d] = sp;
}

// ---------- chunked selective scan ----------
// phase A: per (bk,chunk,d): P = prod a, Q = h_end with h0=0
__global__ __launch_bounds__(256) void scanA_kernel(const float* __restrict__ delta,
        const float* __restrict__ xs, const float* __restrict__ xdbl,
        const float* __restrict__ A_logs, float* __restrict__ P, float* __restrict__ Q) {
    int half = blockIdx.x & 1;
    int chunk = (blockIdx.x >> 1) & 15;
    int bk = blockIdx.x >> 5;
    int k = bk & 3;
    int d = half * 256 + threadIdx.x;
    __shared__ float Bl[64][16];
    for (int s = threadIdx.x; s < 64 * 16; s += 256) {
        int ll = s >> 4, n = s & 15;
        Bl[ll][n] = xdbl[(size_t)(bk * 1024 + chunk * 64 + ll) * 64 + 32 + n];
    }
    __syncthreads();
    float An[16];
#pragma unroll
    for (int n = 0; n < 16; ++n) An[n] = -__expf(A_logs[(size_t)(k * 512 + d) * 16 + n]);
    float h[16] = {};
    float p[16];
#pragma unroll
    for (int n = 0; n < 16; ++n) p[n] = 1.0f;
    int base = bk * 1024 + chunk * 64;
    for (int ll = 0; ll < 64; ++ll) {
        size_t off = (size_t)(base + ll) * 512 + d;
        float da = delta[off];
        float du = da * xs[off];
#pragma unroll
        for (int n = 0; n < 16; ++n) {
            float a = __expf(da * An[n]);
            h[n] = fmaf(h[n], a, du * Bl[ll][n]);
            p[n] *= a;
        }
    }
    size_t pb = ((size_t)(bk * 16 + chunk) * 16) * 512 + d;
#pragma unroll
    for (int n = 0; n < 16; ++n) { P[pb + n * 512] = p[n]; Q[pb + n * 512] = h[n]; }
}

// phase B: serial combine over 16 chunks -> h_start per chunk
__global__ __launch_bounds__(512) void scanB_kernel(const float* __restrict__ P,
        const float* __restrict__ Q, float* __restrict__ Hst) {
    int bk = blockIdx.x;
    int d = threadIdx.x;
    float h[16] = {};
    for (int chunk = 0; chunk < 16; ++chunk) {
        size_t base = ((size_t)(bk * 16 + chunk) * 16) * 512 + d;
#pragma unroll
        for (int n = 0; n < 16; ++n) {
            Hst[base + n * 512] = h[n];
            h[n] = fmaf(P[base + n * 512], h[n], Q[base + n * 512]);
        }
    }
}

// phase C: replay with correct h_start, y = h.C, += u*D
__global__ __launch_bounds__(256) void scanC_kernel(const float* __restrict__ delta,
        const float* __restrict__ xs, const float* __restrict__ xdbl,
        const float* __restrict__ A_logs, const float* __restrict__ Hst,
        const float* __restrict__ Ds, float* __restrict__ ys) {
    int half = blockIdx.x & 1;
    int chunk = (blockIdx.x >> 1) & 15;
    int bk = blockIdx.x >> 5;
    int k = bk & 3;
    int d = half * 256 + threadIdx.x;
    __shared__ float BC[64][32];             // [ll][0:16]=B, [16:32]=C
    for (int s = threadIdx.x; s < 64 * 32; s += 256) {
        int ll = s >> 5, n = s & 31;
        BC[ll][n] = xdbl[(size_t)(bk * 1024 + chunk * 64 + ll) * 64 + 32 + n];
    }
    __syncthreads();
    float An[16];
#pragma unroll
    for (int n = 0; n < 16; ++n) An[n] = -__expf(A_logs[(size_t)(k * 512 + d) * 16 + n]);
    float h[16];
    size_t hb = ((size_t)(bk * 16 + chunk) * 16) * 512 + d;
#pragma unroll
    for (int n = 0; n < 16; ++n) h[n] = Hst[hb + n * 512];
    float Dv = Ds[k * 512 + d];
    int base = bk * 1024 + chunk * 64;
    for (int ll = 0; ll < 64; ++ll) {
        size_t off = (size_t)(base + ll) * 512 + d;
        float da = delta[off];
        float u = xs[off];
        float du = da * u;
        float y = 0.0f;
#pragma unroll
        for (int n = 0; n < 16; ++n) {
            float a = __expf(da * An[n]);
            h[n] = fmaf(h[n], a, du * BC[ll][n]);
            y = fmaf(h[n], BC[ll][16 + n], y);
        }
        ys[off] = fmaf(u, Dv, y);
    }
}

// ---------- merge fwd/bwd scans + concat z -> T3 tokens (4096 x 1024) ----------
__global__ __launch_bounds__(256) void merge_kernel(const float* __restrict__ ys,
        const float* __restrict__ xz, float* __restrict__ T3) {
    int idx = blockIdx.x * 256 + threadIdx.x;   // (b,nn,l,d)
    int d = idx & 511;
    int l = (idx >> 9) & 1023;
    int nn = (idx >> 19) & 1;
    int b = idx >> 20;
    float v = ys[((size_t)(b * 4 + nn) * 1024 + l) * 512 + d]
            + ys[((size_t)(b * 4 + nn + 2) * 1024 + (1023 - l)) * 512 + d];
    size_t trow = (size_t)(b * 2 + nn) * 1024 + l;
    T3[trow * 1024 + d] = v;
    T3[trow * 1024 + 512 + d] = xz[trow * 1024 + 512 + d];
}

// ---------- launch ----------
extern "C" void kernel_launch(void* const* d_in, const int* in_sizes, int n_in,
                              void* d_out, int out_size, void* d_ws, size_t ws_size,
                              hipStream_t stream) {
    const float* hidden  = (const float*)d_in[0];
    const float* in_bw   = (const float*)d_in[1];
    const float* in_sw   = (const float*)d_in[2];
    const float* in_sc   = (const float*)d_in[3];
    const float* conv_w  = (const float*)d_in[4];
    const float* conv_b  = (const float*)d_in[5];
    const float* x_bw    = (const float*)d_in[6];
    const float* x_sw    = (const float*)d_in[7];
    const float* x_sc    = (const float*)d_in[8];
    const float* dt_w    = (const float*)d_in[9];
    const float* dt_bias = (const float*)d_in[10];
    const float* A_logs  = (const float*)d_in[11];
    const float* Ds      = (const float*)d_in[12];
    const float* out_bw  = (const float*)d_in[13];
    const float* out_sw  = (const float*)d_in[14];
    const float* out_sc  = (const float*)d_in[15];
    float* out = (float*)d_out;
    char* ws = (char*)d_ws;

    // workspace layout (bytes, all 256-aligned); total 120.6 MB
    float* XZ    = (float*)(ws + 0);                       // 4096x1024 f32
    float* XS    = (float*)(ws + 16777216);                // 8x1024x512 f32
    float* XDBL  = (float*)(ws + 33554432);                // 8192x64 f32
    float* DELTA = (float*)(ws + 35651584);                // 8192x512 f32
    float* T3    = (float*)(ws + 52428800);                // 4096x1024 f32
    unsigned short* WC1 = (unsigned short*)(ws + 69206016); // 1024x4608 bf16
    unsigned short* WC2 = (unsigned short*)(ws + 78643200); // 64x4608 bf16
    unsigned short* WC3 = (unsigned short*)(ws + 79233024); // 512x9216 bf16
    unsigned short* FEAT = (unsigned short*)(ws + 88670208); // 4096x4608 bf16 (37.75MB)
    // scan scratch overlays FEAT (dead between kan2 and kan3 feature passes)
    float* P   = (float*)(ws + 88670208);
    float* Q   = (float*)(ws + 88670208 + 4194304);
    float* HST = (float*)(ws + 88670208 + 8388608);
    float* YS  = (float*)(ws + 88670208 + 12582912);

    // fold weights (per-call; inputs are restored before every launch)
    wc_kernel<<<dim3((1024 * 512) / 256), 256, 0, stream>>>(in_bw, in_sw, in_sc, WC1, 1024 * 512);
    wc_kernel<<<dim3((64 * 512) / 256), 256, 0, stream>>>(x_bw, x_sw, x_sc, WC2, 64 * 512);
    wc_kernel<<<dim3((512 * 1024) / 256), 256, 0, stream>>>(out_bw, out_sw, out_sc, WC3, 512 * 1024);

    // kan1: xz = KAN(hidden)
    feat_kernel<<<8192, 256, 0, stream>>>(hidden, FEAT, 4096 * 512);
    gemm64<<<dim3(64, 16), 256, 0, stream>>>(FEAT, WC1, XZ, 4096, 1024, 4608);

    // conv + silu + xs build (fwd + reversed)
    conv_xs_kernel<<<8192, 256, 0, stream>>>(XZ, conv_w, conv_b, XS);

    // kan2: x_dbl = KAN(xs)   (2 token chunks of 4096)
    for (int c = 0; c < 2; ++c) {
        feat_kernel<<<8192, 256, 0, stream>>>(XS + (size_t)c * 4096 * 512, FEAT, 4096 * 512);
        gemm64<<<dim3(64, 1), 256, 0, stream>>>(FEAT, WC2, XDBL + (size_t)c * 4096 * 64, 4096, 64, 4608);
    }

    // delta
    delta_kernel<<<16384, 256, 0, stream>>>(XDBL, dt_w, dt_bias, DELTA);

    // chunked selective scan
    scanA_kernel<<<256, 256, 0, stream>>>(DELTA, XS, XDBL, A_logs, P, Q);
    scanB_kernel<<<8, 512, 0, stream>>>(P, Q, HST);
    scanC_kernel<<<256, 256, 0, stream>>>(DELTA, XS, XDBL, A_logs, HST, Ds, YS);

    // merge + concat z
    merge_kernel<<<8192, 256, 0, stream>>>(YS, XZ, T3);

    // kan3: out = KAN(T3)   (2 token chunks of 2048, K=9216)
    for (int c = 0; c < 2; ++c) {
        feat_kernel<<<8192, 256, 0, stream>>>(T3 + (size_t)c * 2048 * 1024, FEAT, 2048 * 1024);
        gemm64<<<dim3(32, 8), 256, 0, stream>>>(FEAT, WC3, out + (size_t)c * 2048 * 512, 2048, 512, 9216);
    }
}

// Round 3
// 649.527 us; speedup vs baseline: 3.5341x; 3.5341x over previous
//
#include <hip/hip_runtime.h>
#include <stdint.h>

#define DEV __device__ __forceinline__

typedef __attribute__((ext_vector_type(8))) short short8;   // 8 bf16 = 4 VGPRs
typedef __attribute__((ext_vector_type(4))) float f32x4;

// ---------- helpers ----------
DEV unsigned short f2bf(float f) {
    union { float f; uint32_t u; } v; v.f = f;
    uint32_t u = v.u;
    return (unsigned short)((u + 0x7fffu + ((u >> 16) & 1u)) >> 16);  // RNE
}
DEV float silu_f(float x) { return x / (1.0f + __expf(-x)); }

// degree-3 B-spline bases on uniform grid g[j] = 0.4*(j-3) - 1, j=0..11 -> 8 bases
DEV void bspline8(float x, float* bo) {
    float b[11];
#pragma unroll
    for (int j = 0; j < 11; ++j) {
        float gj  = 0.4f * (float)(j - 3) - 1.0f;
        float gj1 = 0.4f * (float)(j - 2) - 1.0f;
        b[j] = (x >= gj && x < gj1) ? 1.0f : 0.0f;
    }
#pragma unroll
    for (int k = 1; k <= 3; ++k) {
        float inv = 1.0f / (0.4f * (float)k);
#pragma unroll
        for (int j = 0; j + k < 11; ++j) {
            float gj  = 0.4f * (float)(j - 3) - 1.0f;      // g[j]
            float gk1 = 0.4f * (float)(j + k - 2) - 1.0f;  // g[j+k+1]
            b[j] = ((x - gj) * b[j] + (gk1 - x) * b[j + 1]) * inv;
        }
    }
#pragma unroll
    for (int j = 0; j < 8; ++j) bo[j] = b[j];
}

// ---------- weight fold: Wc[o, i*9+0]=bw, [i*9+1+j]=sw*sc (bf16) ----------
__global__ __launch_bounds__(256) void wc_kernel(const float* __restrict__ bw,
        const float* __restrict__ sw, const float* __restrict__ sc,
        unsigned short* __restrict__ Wc, int total) {
    int idx = blockIdx.x * 256 + threadIdx.x;       // idx = o*IN + i
    if (idx >= total) return;
    float scale = sc[idx];
    unsigned short* o = Wc + (size_t)idx * 9;
    o[0] = f2bf(bw[idx]);
    const float* s = sw + (size_t)idx * 8;
#pragma unroll
    for (int j = 0; j < 8; ++j) o[1 + j] = f2bf(s[j] * scale);
}

// ---------- feature expansion: F[t, i*9+j] (bf16), X contiguous (t,i) ----------
__global__ __launch_bounds__(256) void feat_kernel(const float* __restrict__ X,
        unsigned short* __restrict__ F, int total) {
    int idx = blockIdx.x * 256 + threadIdx.x;
    if (idx >= total) return;
    float x = X[idx];
    unsigned short* o = F + (size_t)idx * 9;
    o[0] = f2bf(silu_f(x));
    float bo[8];
    bspline8(x, bo);
#pragma unroll
    for (int j = 0; j < 8; ++j) o[1 + j] = f2bf(bo[j]);
}

// ---------- MFMA GEMM: C[M,N] = A[M,K](bf16) * B[N,K](bf16)^T, f32 acc ----------
// 256 threads = 4 waves in 2x2; per-wave tile (BM/2)x(BN/2); BK=32.
// LDS linear [row][32] bf16; staged via global_load_lds width-16 (m97 structure).
template<int BM, int BN>
__global__ __launch_bounds__(256) void gemm_mfma(const unsigned short* __restrict__ A,
        const unsigned short* __restrict__ B, float* __restrict__ C,
        int M, int N, int K) {
    constexpr int FRM = BM / 32;          // fragments per wave in M
    constexpr int FRN = BN / 32;          // fragments per wave in N
    __shared__ unsigned short As[BM * 32];
    __shared__ unsigned short Bs[BN * 32];
    const int tid = threadIdx.x;
    const int lane = tid & 63;
    const int w = tid >> 6;
    const int wr = w >> 1, wc = w & 1;
    const int bm = blockIdx.x * BM, bn = blockIdx.y * BN;
    const int frow = lane & 15;           // A/B fragment row (M or N dim)
    const int kq = (lane >> 4) * 8;       // k quarter (8 contiguous bf16)

    f32x4 acc[FRM][FRN];
#pragma unroll
    for (int m = 0; m < FRM; ++m)
#pragma unroll
        for (int n = 0; n < FRN; ++n)
            acc[m][n] = (f32x4){0.f, 0.f, 0.f, 0.f};

    for (int k0 = 0; k0 < K; k0 += 32) {
        // stage A tile (BM x 32) and B tile (BN x 32) -> LDS, 16B per lane
#pragma unroll
        for (int r = 0; r < (BM * 64) / 4096; ++r) {
            int bo = r * 4096 + tid * 16;       // byte offset in LDS tile
            int row = bo >> 6, cb = bo & 63;    // 64B per row
            __builtin_amdgcn_global_load_lds(
                (const __attribute__((address_space(1))) void*)((const char*)A + ((size_t)(bm + row) * K + k0) * 2 + cb),
                (__attribute__((address_space(3))) void*)((char*)As + bo), 16, 0, 0);
        }
#pragma unroll
        for (int r = 0; r < (BN * 64) / 4096; ++r) {
            int bo = r * 4096 + tid * 16;
            int row = bo >> 6, cb = bo & 63;
            __builtin_amdgcn_global_load_lds(
                (const __attribute__((address_space(1))) void*)((const char*)B + ((size_t)(bn + row) * K + k0) * 2 + cb),
                (__attribute__((address_space(3))) void*)((char*)Bs + bo), 16, 0, 0);
        }
        __syncthreads();                        // drains vmcnt before reads

        short8 af[FRM], bf[FRN];
#pragma unroll
        for (int m = 0; m < FRM; ++m)
            af[m] = *(const short8*)&As[(wr * (BM / 2) + m * 16 + frow) * 32 + kq];
#pragma unroll
        for (int n = 0; n < FRN; ++n)
            bf[n] = *(const short8*)&Bs[(wc * (BN / 2) + n * 16 + frow) * 32 + kq];
#pragma unroll
        for (int m = 0; m < FRM; ++m)
#pragma unroll
            for (int n = 0; n < FRN; ++n)
                acc[m][n] = __builtin_amdgcn_mfma_f32_16x16x32_bf16(af[m], bf[n], acc[m][n], 0, 0, 0);
        __syncthreads();
    }

    // epilogue: C/D layout col=lane&15, row=(lane>>4)*4+reg  [m89/m91 verified]
    const int crow = (lane >> 4) * 4;
    const int ccol = lane & 15;
#pragma unroll
    for (int m = 0; m < FRM; ++m)
#pragma unroll
        for (int n = 0; n < FRN; ++n) {
            int gr = bm + wr * (BM / 2) + m * 16 + crow;
            int gc = bn + wc * (BN / 2) + n * 16 + ccol;
#pragma unroll
            for (int r = 0; r < 4; ++r)
                C[(size_t)(gr + r) * N + gc] = acc[m][n][r];
        }
}

// ---------- causal depthwise conv1d + SiLU + build xs (fwd & L-reversed) ----------
__global__ __launch_bounds__(256) void conv_xs_kernel(const float* __restrict__ xz,
        const float* __restrict__ cw, const float* __restrict__ cb,
        float* __restrict__ xs) {
    int idx = blockIdx.x * 256 + threadIdx.x;     // (bn, l, d)
    int d = idx & 511;
    int l = (idx >> 9) & 1023;
    int bn = idx >> 19;                           // 0..3
    const float* xcol = xz + (size_t)(bn * 1024) * 1024 + d;  // x = first half of xz row
    float acc = cb[d];
#pragma unroll
    for (int h = 0; h < 4; ++h) {
        int ls = l - 3 + h;
        float xv = (ls >= 0) ? xcol[(size_t)ls * 1024] : 0.0f;
        acc = fmaf(cw[d * 4 + h], xv, acc);
    }
    float v = silu_f(acc);
    int b = bn >> 1, nn = bn & 1;
    xs[((size_t)(b * 4 + nn) * 1024 + l) * 512 + d] = v;
    xs[((size_t)(b * 4 + nn + 2) * 1024 + (1023 - l)) * 512 + d] = v;
}

// ---------- delta = softplus(dt @ dt_w^T + dt_bias[k]) ----------
__global__ __launch_bounds__(256) void delta_kernel(const float* __restrict__ xdbl,
        const float* __restrict__ dtw, const float* __restrict__ dtb,
        float* __restrict__ delta) {
    int t = blockIdx.x >> 1;                 // token 0..8191
    int half = blockIdx.x & 1;
    int d = half * 256 + threadIdx.x;
    __shared__ float dtv[32];
    if (threadIdx.x < 32) dtv[threadIdx.x] = xdbl[(size_t)t * 64 + threadIdx.x];
    __syncthreads();
    const float* w = dtw + (size_t)d * 32;
    float acc = 0.0f;
#pragma unroll
    for (int r = 0; r < 32; r += 4) {
        float4 wv = *(const float4*)(w + r);
        acc = fmaf(dtv[r], wv.x, acc);
        acc = fmaf(dtv[r + 1], wv.y, acc);
        acc = fmaf(dtv[r + 2], wv.z, acc);
        acc = fmaf(dtv[r + 3], wv.w, acc);
    }
    int k = (t >> 10) & 3;
    float x = acc + dtb[k * 512 + d];
    float sp = (x > 20.0f) ? x : log1pf(__expf(x));
    delta[(size_t)t * 512 + d] = sp;
}

// ---------- chunked selective scan ----------
// phase A: per (bk,chunk,d): P = prod a, Q = h_end with h0=0
__global__ __launch_bounds__(256) void scanA_kernel(const float* __restrict__ delta,
        const float* __restrict__ xs, const float* __restrict__ xdbl,
        const float* __restrict__ A_logs, float* __restrict__ P, float* __restrict__ Q) {
    int half = blockIdx.x & 1;
    int chunk = (blockIdx.x >> 1) & 15;
    int bk = blockIdx.x >> 5;
    int k = bk & 3;
    int d = half * 256 + threadIdx.x;
    __shared__ float Bl[64][16];
    for (int s = threadIdx.x; s < 64 * 16; s += 256) {
        int ll = s >> 4, n = s & 15;
        Bl[ll][n] = xdbl[(size_t)(bk * 1024 + chunk * 64 + ll) * 64 + 32 + n];
    }
    __syncthreads();
    float An[16];
#pragma unroll
    for (int n = 0; n < 16; ++n) An[n] = -__expf(A_logs[(size_t)(k * 512 + d) * 16 + n]);
    float h[16] = {};
    float p[16];
#pragma unroll
    for (int n = 0; n < 16; ++n) p[n] = 1.0f;
    int base = bk * 1024 + chunk * 64;
    for (int ll = 0; ll < 64; ++ll) {
        size_t off = (size_t)(base + ll) * 512 + d;
        float da = delta[off];
        float du = da * xs[off];
#pragma unroll
        for (int n = 0; n < 16; ++n) {
            float a = __expf(da * An[n]);
            h[n] = fmaf(h[n], a, du * Bl[ll][n]);
            p[n] *= a;
        }
    }
    size_t pb = ((size_t)(bk * 16 + chunk) * 16) * 512 + d;
#pragma unroll
    for (int n = 0; n < 16; ++n) { P[pb + n * 512] = p[n]; Q[pb + n * 512] = h[n]; }
}

// phase B: serial combine over 16 chunks -> h_start per chunk
__global__ __launch_bounds__(512) void scanB_kernel(const float* __restrict__ P,
        const float* __restrict__ Q, float* __restrict__ Hst) {
    int bk = blockIdx.x;
    int d = threadIdx.x;
    float h[16] = {};
    for (int chunk = 0; chunk < 16; ++chunk) {
        size_t base = ((size_t)(bk * 16 + chunk) * 16) * 512 + d;
#pragma unroll
        for (int n = 0; n < 16; ++n) {
            Hst[base + n * 512] = h[n];
            h[n] = fmaf(P[base + n * 512], h[n], Q[base + n * 512]);
        }
    }
}

// phase C: replay with correct h_start, y = h.C, += u*D  (ys written IN-PLACE over xs)
__global__ __launch_bounds__(256) void scanC_kernel(const float* __restrict__ delta,
        float* __restrict__ xs, const float* __restrict__ xdbl,
        const float* __restrict__ A_logs, const float* __restrict__ Hst,
        const float* __restrict__ Ds) {
    int half = blockIdx.x & 1;
    int chunk = (blockIdx.x >> 1) & 15;
    int bk = blockIdx.x >> 5;
    int k = bk & 3;
    int d = half * 256 + threadIdx.x;
    __shared__ float BC[64][32];             // [ll][0:16]=B, [16:32]=C
    for (int s = threadIdx.x; s < 64 * 32; s += 256) {
        int ll = s >> 5, n = s & 31;
        BC[ll][n] = xdbl[(size_t)(bk * 1024 + chunk * 64 + ll) * 64 + 32 + n];
    }
    __syncthreads();
    float An[16];
#pragma unroll
    for (int n = 0; n < 16; ++n) An[n] = -__expf(A_logs[(size_t)(k * 512 + d) * 16 + n]);
    float h[16];
    size_t hb = ((size_t)(bk * 16 + chunk) * 16) * 512 + d;
#pragma unroll
    for (int n = 0; n < 16; ++n) h[n] = Hst[hb + n * 512];
    float Dv = Ds[k * 512 + d];
    int base = bk * 1024 + chunk * 64;
    for (int ll = 0; ll < 64; ++ll) {
        size_t off = (size_t)(base + ll) * 512 + d;
        float da = delta[off];
        float u = xs[off];
        float du = da * u;
        float y = 0.0f;
#pragma unroll
        for (int n = 0; n < 16; ++n) {
            float a = __expf(da * An[n]);
            h[n] = fmaf(h[n], a, du * BC[ll][n]);
            y = fmaf(h[n], BC[ll][16 + n], y);
        }
        xs[off] = fmaf(u, Dv, y);            // in-place: each off read+written once
    }
}

// ---------- merge fwd/bwd scans IN-PLACE into xz x-half (z-half already = T3 z) ----------
__global__ __launch_bounds__(256) void merge_kernel(const float* __restrict__ ys,
        float* __restrict__ xz) {
    int idx = blockIdx.x * 256 + threadIdx.x;   // (b,nn,l,d)
    int d = idx & 511;
    int l = (idx >> 9) & 1023;
    int nn = (idx >> 19) & 1;
    int b = idx >> 20;
    float v = ys[((size_t)(b * 4 + nn) * 1024 + l) * 512 + d]
            + ys[((size_t)(b * 4 + nn + 2) * 1024 + (1023 - l)) * 512 + d];
    size_t trow = (size_t)(b * 2 + nn) * 1024 + l;
    xz[trow * 1024 + d] = v;                    // T3 := [merged_y | z]
}

// ---------- launch ----------
extern "C" void kernel_launch(void* const* d_in, const int* in_sizes, int n_in,
                              void* d_out, int out_size, void* d_ws, size_t ws_size,
                              hipStream_t stream) {
    const float* hidden  = (const float*)d_in[0];
    const float* in_bw   = (const float*)d_in[1];
    const float* in_sw   = (const float*)d_in[2];
    const float* in_sc   = (const float*)d_in[3];
    const float* conv_w  = (const float*)d_in[4];
    const float* conv_b  = (const float*)d_in[5];
    const float* x_bw    = (const float*)d_in[6];
    const float* x_sw    = (const float*)d_in[7];
    const float* x_sc    = (const float*)d_in[8];
    const float* dt_w    = (const float*)d_in[9];
    const float* dt_bias = (const float*)d_in[10];
    const float* A_logs  = (const float*)d_in[11];
    const float* Ds      = (const float*)d_in[12];
    const float* out_bw  = (const float*)d_in[13];
    const float* out_sw  = (const float*)d_in[14];
    const float* out_sc  = (const float*)d_in[15];
    float* out = (float*)d_out;
    char* ws = (char*)d_ws;

    // layout (bytes):
    //   0        XZ (16MB)  -- becomes T3 in-place at merge
    //  16M       XS (16MB)  -- becomes YS in-place at scanC
    //  32M       XDBL (2MB)
    //  34M       DELTA (16MB)
    //  50M       WCA (9.44MB)  WC1, later overwritten by WC3 (same size)
    //  61865984  WC2 (0.56MB)
    //  62455808  FEAT (37.75MB tierB / 75.5MB tierA); P/Q/HST overlay during scan
    float* XZ    = (float*)(ws + 0);
    float* XS    = (float*)(ws + 16777216);
    float* XDBL  = (float*)(ws + 33554432);
    float* DELTA = (float*)(ws + 35651584);
    unsigned short* WCA = (unsigned short*)(ws + 52428800);
    unsigned short* WC2 = (unsigned short*)(ws + 61865984);
    unsigned short* FEAT = (unsigned short*)(ws + 62455808);
    float* P   = (float*)(ws + 62455808);
    float* Q   = (float*)(ws + 62455808 + 4194304);
    float* HST = (float*)(ws + 62455808 + 8388608);

    const bool tierA = ws_size >= (size_t)62455808 + 75497472;  // fused kan2/kan3 fit

    // fold weights for kan1, kan2
    wc_kernel<<<dim3((1024 * 512) / 256), 256, 0, stream>>>(in_bw, in_sw, in_sc, WCA, 1024 * 512);
    wc_kernel<<<dim3((64 * 512) / 256), 256, 0, stream>>>(x_bw, x_sw, x_sc, WC2, 64 * 512);

    // kan1: xz = KAN(hidden)   M=4096 N=1024 K=4608
    feat_kernel<<<8192, 256, 0, stream>>>(hidden, FEAT, 4096 * 512);
    gemm_mfma<128, 128><<<dim3(32, 8), 256, 0, stream>>>(FEAT, WCA, XZ, 4096, 1024, 4608);

    // fold kan3 weights into WCA (WC1 dead after gemm1; identical size)
    wc_kernel<<<dim3((512 * 1024) / 256), 256, 0, stream>>>(out_bw, out_sw, out_sc, WCA, 512 * 1024);

    // conv + silu + xs build (fwd + reversed)
    conv_xs_kernel<<<8192, 256, 0, stream>>>(XZ, conv_w, conv_b, XS);

    // kan2: x_dbl = KAN(xs)   M=8192 N=64 K=4608
    {
        const int nk2 = tierA ? 1 : 2;
        const int tok = 8192 / nk2;
        for (int c = 0; c < nk2; ++c) {
            feat_kernel<<<(tok * 512) / 256, 256, 0, stream>>>(XS + (size_t)c * tok * 512, FEAT, tok * 512);
            gemm_mfma<64, 64><<<dim3(tok / 64, 1), 256, 0, stream>>>(FEAT, WC2, XDBL + (size_t)c * tok * 64, tok, 64, 4608);
        }
    }

    // delta
    delta_kernel<<<16384, 256, 0, stream>>>(XDBL, dt_w, dt_bias, DELTA);

    // chunked selective scan (YS in-place over XS)
    scanA_kernel<<<256, 256, 0, stream>>>(DELTA, XS, XDBL, A_logs, P, Q);
    scanB_kernel<<<8, 512, 0, stream>>>(P, Q, HST);
    scanC_kernel<<<256, 256, 0, stream>>>(DELTA, XS, XDBL, A_logs, HST, Ds);

    // merge into XZ x-half (T3 := XZ)
    merge_kernel<<<8192, 256, 0, stream>>>(XS, XZ);

    // kan3: out = KAN(T3)   M=4096 N=512 K=9216
    {
        const int nk3 = tierA ? 1 : 2;
        const int tok = 4096 / nk3;
        for (int c = 0; c < nk3; ++c) {
            feat_kernel<<<(tok * 1024) / 256, 256, 0, stream>>>(XZ + (size_t)c * tok * 1024, FEAT, tok * 1024);
            gemm_mfma<64, 128><<<dim3(tok / 64, 4), 256, 0, stream>>>(FEAT, WCA, out + (size_t)c * tok * 512, tok, 512, 9216);
        }
    }
}

// Round 4
// 524.648 us; speedup vs baseline: 4.3753x; 1.2380x over previous
//
#include <hip/hip_runtime.h>
#include <stdint.h>

#define DEV __device__ __forceinline__

typedef __attribute__((ext_vector_type(8))) short short8;   // 8 bf16 = 4 VGPRs
typedef __attribute__((ext_vector_type(4))) float f32x4;

// ---------- helpers ----------
DEV unsigned short f2bf(float f) {
    union { float f; uint32_t u; } v; v.f = f;
    uint32_t u = v.u;
    return (unsigned short)((u + 0x7fffu + ((u >> 16) & 1u)) >> 16);  // RNE
}
DEV float silu_f(float x) { return x / (1.0f + __expf(-x)); }

// degree-3 B-spline bases on uniform grid g[j] = 0.4*(j-3) - 1, j=0..11 -> 8 bases
DEV void bspline8(float x, float* bo) {
    float b[11];
#pragma unroll
    for (int j = 0; j < 11; ++j) {
        float gj  = 0.4f * (float)(j - 3) - 1.0f;
        float gj1 = 0.4f * (float)(j - 2) - 1.0f;
        b[j] = (x >= gj && x < gj1) ? 1.0f : 0.0f;
    }
#pragma unroll
    for (int k = 1; k <= 3; ++k) {
        float inv = 1.0f / (0.4f * (float)k);
#pragma unroll
        for (int j = 0; j + k < 11; ++j) {
            float gj  = 0.4f * (float)(j - 3) - 1.0f;      // g[j]
            float gk1 = 0.4f * (float)(j + k - 2) - 1.0f;  // g[j+k+1]
            b[j] = ((x - gj) * b[j] + (gk1 - x) * b[j + 1]) * inv;
        }
    }
#pragma unroll
    for (int j = 0; j < 8; ++j) bo[j] = b[j];
}

// ---------- zero fill (for atomic-accumulated outputs; ws/out are poisoned) ----------
__global__ __launch_bounds__(256) void zero_kernel(float4* __restrict__ p, int n4) {
    int i = blockIdx.x * 256 + threadIdx.x;
    if (i < n4) p[i] = make_float4(0.f, 0.f, 0.f, 0.f);
}

// ---------- weight fold: Wc[o, i*9+0]=bw, [i*9+1+j]=sw*sc (bf16) ----------
__global__ __launch_bounds__(256) void wc_kernel(const float* __restrict__ bw,
        const float* __restrict__ sw, const float* __restrict__ sc,
        unsigned short* __restrict__ Wc, int total) {
    int idx = blockIdx.x * 256 + threadIdx.x;       // idx = o*IN + i
    if (idx >= total) return;
    float scale = sc[idx];
    unsigned short* o = Wc + (size_t)idx * 9;
    o[0] = f2bf(bw[idx]);
    const float* s = sw + (size_t)idx * 8;
#pragma unroll
    for (int j = 0; j < 8; ++j) o[1 + j] = f2bf(s[j] * scale);
}

// ---------- feature expansion: F[t, i*9+j] (bf16), X contiguous (t,i) ----------
__global__ __launch_bounds__(256) void feat_kernel(const float* __restrict__ X,
        unsigned short* __restrict__ F, int total) {
    int idx = blockIdx.x * 256 + threadIdx.x;
    if (idx >= total) return;
    float x = X[idx];
    unsigned short* o = F + (size_t)idx * 9;
    o[0] = f2bf(silu_f(x));
    float bo[8];
    bspline8(x, bo);
#pragma unroll
    for (int j = 0; j < 8; ++j) o[1 + j] = f2bf(bo[j]);
}

// ---------- MFMA GEMM with DEPTH-deep global_load_lds pipeline ----------
// C[M,N] (+)= A[M,K'](bf16) * B[N,K'](bf16)^T over K-chunk blockIdx.z.
// 256 threads = 4 waves (2x2); per-wave tile (BM/2)x(BN/2); BK=32.
// NB = DEPTH+2 LDS buffers; counted s_waitcnt vmcnt(N) (never 0 in main loop);
// one asm s_barrier per K-step (NB=DEPTH+2 makes stage-write vs read WAR safe).
template<int BM, int BN, int DEPTH, bool ATOMIC>
__global__ __launch_bounds__(256) void gemm_mfma2(const unsigned short* __restrict__ A,
        const unsigned short* __restrict__ B, float* __restrict__ C,
        int M, int N, int K, int klen) {
    constexpr int NB  = DEPTH + 2;
    constexpr int FRM = BM / 32;
    constexpr int FRN = BN / 32;
    constexpr int GLA = (BM * 64) / 4096;   // global_load_lds insts per stage (A)
    constexpr int GLB = (BN * 64) / 4096;
    constexpr int GL  = GLA + GLB;          // per-wave outstanding per stage
    constexpr int LDA = BM * 32;            // elements per A buffer
    constexpr int LDB = BN * 32;
    __shared__ unsigned short As[NB * LDA];
    __shared__ unsigned short Bs[NB * LDB];

    const int tid = threadIdx.x;
    const int lane = tid & 63;
    const int w = tid >> 6;
    const int wr = w >> 1, wc = w & 1;
    const int bm = blockIdx.x * BM, bn = blockIdx.y * BN;
    const int kbase = blockIdx.z * klen;
    const int NT = klen / 32;
    const int frow = lane & 15;
    const int kq = (lane >> 4) * 8;

    f32x4 acc[FRM][FRN];
#pragma unroll
    for (int m = 0; m < FRM; ++m)
#pragma unroll
        for (int n = 0; n < FRN; ++n)
            acc[m][n] = (f32x4){0.f, 0.f, 0.f, 0.f};

    auto stage = [&](int t, int buf) {
        const int k0 = kbase + t * 32;
#pragma unroll
        for (int r = 0; r < GLA; ++r) {
            int bo = r * 4096 + tid * 16;
            int row = bo >> 6, cb = bo & 63;
            __builtin_amdgcn_global_load_lds(
                (const __attribute__((address_space(1))) void*)((const char*)A + ((size_t)(bm + row) * K + k0) * 2 + cb),
                (__attribute__((address_space(3))) void*)((char*)As + (size_t)buf * LDA * 2 + bo), 16, 0, 0);
        }
#pragma unroll
        for (int r = 0; r < GLB; ++r) {
            int bo = r * 4096 + tid * 16;
            int row = bo >> 6, cb = bo & 63;
            __builtin_amdgcn_global_load_lds(
                (const __attribute__((address_space(1))) void*)((const char*)B + ((size_t)(bn + row) * K + k0) * 2 + cb),
                (__attribute__((address_space(3))) void*)((char*)Bs + (size_t)buf * LDB * 2 + bo), 16, 0, 0);
        }
    };

    auto compute = [&](int buf) {
        const unsigned short* as = As + (size_t)buf * LDA;
        const unsigned short* bs = Bs + (size_t)buf * LDB;
        short8 af[FRM], bf[FRN];
#pragma unroll
        for (int m = 0; m < FRM; ++m)
            af[m] = *(const short8*)&as[(wr * (BM / 2) + m * 16 + frow) * 32 + kq];
#pragma unroll
        for (int n = 0; n < FRN; ++n)
            bf[n] = *(const short8*)&bs[(wc * (BN / 2) + n * 16 + frow) * 32 + kq];
#pragma unroll
        for (int m = 0; m < FRM; ++m)
#pragma unroll
            for (int n = 0; n < FRN; ++n)
                acc[m][n] = __builtin_amdgcn_mfma_f32_16x16x32_bf16(af[m], bf[n], acc[m][n], 0, 0, 0);
    };

    // prologue: stage 0..DEPTH-1
    for (int t = 0; t < DEPTH; ++t) stage(t, t);

    int rb = 0;                 // read buffer  (= t % NB)
    int sb = DEPTH;             // stage buffer (= (t+DEPTH) % NB)
    int t = 0;
    for (; t + DEPTH < NT; ++t) {
        stage(t + DEPTH, sb);
        // wait until my slice of stage t is done (DEPTH newer stages allowed in flight)
        asm volatile("s_waitcnt vmcnt(%0)" :: "i"(DEPTH * GL) : "memory");
        asm volatile("s_barrier" ::: "memory");   // all waves' stage-t slices done
        compute(rb);
        rb = (rb + 1 == NB) ? 0 : rb + 1;
        sb = (sb + 1 == NB) ? 0 : sb + 1;
    }
    // epilogue: drain remaining DEPTH tiles
    for (; t < NT; ++t) {
        asm volatile("s_waitcnt vmcnt(0)" ::: "memory");
        asm volatile("s_barrier" ::: "memory");
        compute(rb);
        rb = (rb + 1 == NB) ? 0 : rb + 1;
    }

    // C/D layout: col=lane&15, row=(lane>>4)*4+reg  [m89/m91 verified]
    const int crow = (lane >> 4) * 4;
    const int ccol = lane & 15;
#pragma unroll
    for (int m = 0; m < FRM; ++m)
#pragma unroll
        for (int n = 0; n < FRN; ++n) {
            int gr = bm + wr * (BM / 2) + m * 16 + crow;
            int gc = bn + wc * (BN / 2) + n * 16 + ccol;
#pragma unroll
            for (int r = 0; r < 4; ++r) {
                if (ATOMIC) atomicAdd(&C[(size_t)(gr + r) * N + gc], acc[m][n][r]);
                else        C[(size_t)(gr + r) * N + gc] = acc[m][n][r];
            }
        }
}

// ---------- causal depthwise conv1d + SiLU + build xs (fwd & L-reversed) ----------
__global__ __launch_bounds__(256) void conv_xs_kernel(const float* __restrict__ xz,
        const float* __restrict__ cw, const float* __restrict__ cb,
        float* __restrict__ xs) {
    int idx = blockIdx.x * 256 + threadIdx.x;     // (bn, l, d)
    int d = idx & 511;
    int l = (idx >> 9) & 1023;
    int bn = idx >> 19;                           // 0..3
    const float* xcol = xz + (size_t)(bn * 1024) * 1024 + d;  // x = first half of xz row
    float acc = cb[d];
#pragma unroll
    for (int h = 0; h < 4; ++h) {
        int ls = l - 3 + h;
        float xv = (ls >= 0) ? xcol[(size_t)ls * 1024] : 0.0f;
        acc = fmaf(cw[d * 4 + h], xv, acc);
    }
    float v = silu_f(acc);
    int b = bn >> 1, nn = bn & 1;
    xs[((size_t)(b * 4 + nn) * 1024 + l) * 512 + d] = v;
    xs[((size_t)(b * 4 + nn + 2) * 1024 + (1023 - l)) * 512 + d] = v;
}

// ---------- delta = softplus(dt @ dt_w^T + dt_bias[k]) ----------
__global__ __launch_bounds__(256) void delta_kernel(const float* __restrict__ xdbl,
        const float* __restrict__ dtw, const float* __restrict__ dtb,
        float* __restrict__ delta) {
    int t = blockIdx.x >> 1;                 // token 0..8191
    int half = blockIdx.x & 1;
    int d = half * 256 + threadIdx.x;
    __shared__ float dtv[32];
    if (threadIdx.x < 32) dtv[threadIdx.x] = xdbl[(size_t)t * 64 + threadIdx.x];
    __syncthreads();
    const float* w = dtw + (size_t)d * 32;
    float acc = 0.0f;
#pragma unroll
    for (int r = 0; r < 32; r += 4) {
        float4 wv = *(const float4*)(w + r);
        acc = fmaf(dtv[r], wv.x, acc);
        acc = fmaf(dtv[r + 1], wv.y, acc);
        acc = fmaf(dtv[r + 2], wv.z, acc);
        acc = fmaf(dtv[r + 3], wv.w, acc);
    }
    int k = (t >> 10) & 3;
    float x = acc + dtb[k * 512 + d];
    float sp = (x > 20.0f) ? x : log1pf(__expf(x));
    delta[(size_t)t * 512 + d] = sp;
}

// ---------- chunked selective scan ----------
// phase A: per (bk,chunk,d): P = prod a, Q = h_end with h0=0
__global__ __launch_bounds__(256) void scanA_kernel(const float* __restrict__ delta,
        const float* __restrict__ xs, const float* __restrict__ xdbl,
        const float* __restrict__ A_logs, float* __restrict__ P, float* __restrict__ Q) {
    int half = blockIdx.x & 1;
    int chunk = (blockIdx.x >> 1) & 15;
    int bk = blockIdx.x >> 5;
    int k = bk & 3;
    int d = half * 256 + threadIdx.x;
    __shared__ float Bl[64][16];
    for (int s = threadIdx.x; s < 64 * 16; s += 256) {
        int ll = s >> 4, n = s & 15;
        Bl[ll][n] = xdbl[(size_t)(bk * 1024 + chunk * 64 + ll) * 64 + 32 + n];
    }
    __syncthreads();
    float An[16];
#pragma unroll
    for (int n = 0; n < 16; ++n) An[n] = -__expf(A_logs[(size_t)(k * 512 + d) * 16 + n]);
    float h[16] = {};
    float p[16];
#pragma unroll
    for (int n = 0; n < 16; ++n) p[n] = 1.0f;
    int base = bk * 1024 + chunk * 64;
    for (int ll = 0; ll < 64; ++ll) {
        size_t off = (size_t)(base + ll) * 512 + d;
        float da = delta[off];
        float du = da * xs[off];
#pragma unroll
        for (int n = 0; n < 16; ++n) {
            float a = __expf(da * An[n]);
            h[n] = fmaf(h[n], a, du * Bl[ll][n]);
            p[n] *= a;
        }
    }
    size_t pb = ((size_t)(bk * 16 + chunk) * 16) * 512 + d;
#pragma unroll
    for (int n = 0; n < 16; ++n) { P[pb + n * 512] = p[n]; Q[pb + n * 512] = h[n]; }
}

// phase B: serial combine over 16 chunks -> h_start per chunk
__global__ __launch_bounds__(512) void scanB_kernel(const float* __restrict__ P,
        const float* __restrict__ Q, float* __restrict__ Hst) {
    int bk = blockIdx.x;
    int d = threadIdx.x;
    float h[16] = {};
    for (int chunk = 0; chunk < 16; ++chunk) {
        size_t base = ((size_t)(bk * 16 + chunk) * 16) * 512 + d;
#pragma unroll
        for (int n = 0; n < 16; ++n) {
            Hst[base + n * 512] = h[n];
            h[n] = fmaf(P[base + n * 512], h[n], Q[base + n * 512]);
        }
    }
}

// phase C: replay with correct h_start, y = h.C, += u*D  (ys written IN-PLACE over xs)
__global__ __launch_bounds__(256) void scanC_kernel(const float* __restrict__ delta,
        float* __restrict__ xs, const float* __restrict__ xdbl,
        const float* __restrict__ A_logs, const float* __restrict__ Hst,
        const float* __restrict__ Ds) {
    int half = blockIdx.x & 1;
    int chunk = (blockIdx.x >> 1) & 15;
    int bk = blockIdx.x >> 5;
    int k = bk & 3;
    int d = half * 256 + threadIdx.x;
    __shared__ float BC[64][32];             // [ll][0:16]=B, [16:32]=C
    for (int s = threadIdx.x; s < 64 * 32; s += 256) {
        int ll = s >> 5, n = s & 31;
        BC[ll][n] = xdbl[(size_t)(bk * 1024 + chunk * 64 + ll) * 64 + 32 + n];
    }
    __syncthreads();
    float An[16];
#pragma unroll
    for (int n = 0; n < 16; ++n) An[n] = -__expf(A_logs[(size_t)(k * 512 + d) * 16 + n]);
    float h[16];
    size_t hb = ((size_t)(bk * 16 + chunk) * 16) * 512 + d;
#pragma unroll
    for (int n = 0; n < 16; ++n) h[n] = Hst[hb + n * 512];
    float Dv = Ds[k * 512 + d];
    int base = bk * 1024 + chunk * 64;
    for (int ll = 0; ll < 64; ++ll) {
        size_t off = (size_t)(base + ll) * 512 + d;
        float da = delta[off];
        float u = xs[off];
        float du = da * u;
        float y = 0.0f;
#pragma unroll
        for (int n = 0; n < 16; ++n) {
            float a = __expf(da * An[n]);
            h[n] = fmaf(h[n], a, du * BC[ll][n]);
            y = fmaf(h[n], BC[ll][16 + n], y);
        }
        xs[off] = fmaf(u, Dv, y);            // in-place: each off read+written once
    }
}

// ---------- merge fwd/bwd scans IN-PLACE into xz x-half (z-half already = T3 z) ----------
__global__ __launch_bounds__(256) void merge_kernel(const float* __restrict__ ys,
        float* __restrict__ xz) {
    int idx = blockIdx.x * 256 + threadIdx.x;   // (b,nn,l,d)
    int d = idx & 511;
    int l = (idx >> 9) & 1023;
    int nn = (idx >> 19) & 1;
    int b = idx >> 20;
    float v = ys[((size_t)(b * 4 + nn) * 1024 + l) * 512 + d]
            + ys[((size_t)(b * 4 + nn + 2) * 1024 + (1023 - l)) * 512 + d];
    size_t trow = (size_t)(b * 2 + nn) * 1024 + l;
    xz[trow * 1024 + d] = v;                    // T3 := [merged_y | z]
}

// ---------- launch ----------
extern "C" void kernel_launch(void* const* d_in, const int* in_sizes, int n_in,
                              void* d_out, int out_size, void* d_ws, size_t ws_size,
                              hipStream_t stream) {
    const float* hidden  = (const float*)d_in[0];
    const float* in_bw   = (const float*)d_in[1];
    const float* in_sw   = (const float*)d_in[2];
    const float* in_sc   = (const float*)d_in[3];
    const float* conv_w  = (const float*)d_in[4];
    const float* conv_b  = (const float*)d_in[5];
    const float* x_bw    = (const float*)d_in[6];
    const float* x_sw    = (const float*)d_in[7];
    const float* x_sc    = (const float*)d_in[8];
    const float* dt_w    = (const float*)d_in[9];
    const float* dt_bias = (const float*)d_in[10];
    const float* A_logs  = (const float*)d_in[11];
    const float* Ds      = (const float*)d_in[12];
    const float* out_bw  = (const float*)d_in[13];
    const float* out_sw  = (const float*)d_in[14];
    const float* out_sc  = (const float*)d_in[15];
    float* out = (float*)d_out;
    char* ws = (char*)d_ws;

    // layout (bytes), peak 121,176,064 (< 126,418,944 proven in R0):
    //   0          XZ   16M   (kan1 out -> T3 in-place at merge)
    //  16,777,216  XS   16M   (conv out -> YS in-place at scanC)
    //  33,554,432  XDBL  2M   (atomic-accumulated, zeroed each call)
    //  35,651,584  FEAT zone 75.5M (FEAT1/FEAT2/FEAT3; overlaid by DELTA/P/Q/HST
    //                              between gemm2 and feat3)
    // 111,149,056  WCbuf 9.44M (WC1 for kan1, refolded to WC3 after gemm1)
    // 120,586,240  WC2  0.56M
    float* XZ    = (float*)(ws + 0);
    float* XS    = (float*)(ws + 16777216);
    float* XDBL  = (float*)(ws + 33554432);
    unsigned short* FEAT = (unsigned short*)(ws + 35651584);
    float* DELTA = (float*)(ws + 35651584);            // overlays FEAT zone head
    float* P     = (float*)(ws + 52428800);
    float* Q     = (float*)(ws + 56623104);
    float* HST   = (float*)(ws + 60817408);
    unsigned short* WCbuf = (unsigned short*)(ws + 111149056);
    unsigned short* WC2   = (unsigned short*)(ws + 120586240);

    // fold weights for kan1, kan2
    wc_kernel<<<dim3((1024 * 512) / 256), 256, 0, stream>>>(in_bw, in_sw, in_sc, WCbuf, 1024 * 512);
    wc_kernel<<<dim3((64 * 512) / 256), 256, 0, stream>>>(x_bw, x_sw, x_sc, WC2, 64 * 512);

    // kan1: xz = KAN(hidden)   M=4096 N=1024 K=4608, grid 512 (2 blocks/CU)
    feat_kernel<<<8192, 256, 0, stream>>>(hidden, FEAT, 4096 * 512);
    gemm_mfma2<128, 64, 3, false><<<dim3(32, 16, 1), 256, 0, stream>>>(FEAT, WCbuf, XZ, 4096, 1024, 4608, 4608);

    // refold WCbuf -> kan3 weights (WC1 dead after gemm1)
    wc_kernel<<<dim3((512 * 1024) / 256), 256, 0, stream>>>(out_bw, out_sw, out_sc, WCbuf, 512 * 1024);

    // conv + silu + xs build (fwd + reversed)
    conv_xs_kernel<<<8192, 256, 0, stream>>>(XZ, conv_w, conv_b, XS);

    // kan2: x_dbl = KAN(xs)   M=8192 N=64 K=4608, split-K x4, grid 512
    feat_kernel<<<16384, 256, 0, stream>>>(XS, FEAT, 8192 * 512);
    zero_kernel<<<512, 256, 0, stream>>>((float4*)XDBL, (8192 * 64) / 4);
    gemm_mfma2<64, 64, 3, true><<<dim3(128, 1, 4), 256, 0, stream>>>(FEAT, WC2, XDBL, 8192, 64, 4608, 1152);

    // delta (overwrites dead FEAT2 head)
    delta_kernel<<<16384, 256, 0, stream>>>(XDBL, dt_w, dt_bias, DELTA);

    // chunked selective scan (YS in-place over XS)
    scanA_kernel<<<256, 256, 0, stream>>>(DELTA, XS, XDBL, A_logs, P, Q);
    scanB_kernel<<<8, 512, 0, stream>>>(P, Q, HST);
    scanC_kernel<<<256, 256, 0, stream>>>(DELTA, XS, XDBL, A_logs, HST, Ds);

    // merge into XZ x-half (T3 := XZ)
    merge_kernel<<<8192, 256, 0, stream>>>(XS, XZ);

    // kan3: out = KAN(T3)   M=4096 N=512 K=9216, split-K x2, grid 512
    feat_kernel<<<16384, 256, 0, stream>>>(XZ, FEAT, 4096 * 1024);
    zero_kernel<<<2048, 256, 0, stream>>>((float4*)out, (4096 * 512) / 4);
    gemm_mfma2<128, 64, 3, true><<<dim3(32, 8, 2), 256, 0, stream>>>(FEAT, WCbuf, out, 4096, 512, 9216, 4608);
}